// Round 8
// baseline (160.962 us; speedup 1.0000x reference)
//
#include <hip/hip_runtime.h>
#include <stdint.h>

typedef __bf16 bf16x8 __attribute__((ext_vector_type(8)));
typedef __bf16 bf16x4 __attribute__((ext_vector_type(4)));
typedef float f32x4 __attribute__((ext_vector_type(4)));
typedef float f32x16 __attribute__((ext_vector_type(16)));

#define PSCALE (0.125f / 2048.0f)

// async global->LDS, 16B per lane. LDS dest must be wave-uniform; HW adds lane*16.
#define GLOAD16(src, dst)                                                      \
  __builtin_amdgcn_global_load_lds(                                            \
      (__attribute__((address_space(1))) void*)const_cast<__bf16*>(src),       \
      (__attribute__((address_space(3))) void*)(dst), 16, 0, 0)

// -------- prep: LayerNorm (blocks 0..8191) + w_qkv transpose (8192..8959)
//          + w_out transpose (8960..9215), all fp32 -> bf16 ----------------
__global__ __launch_bounds__(256) void prep(
    const float* __restrict__ x, const float* __restrict__ lw,
    const float* __restrict__ lb, __bf16* __restrict__ xn,
    const float* __restrict__ w_qkv, __bf16* __restrict__ Wt1,
    const float* __restrict__ w_out, __bf16* __restrict__ Wt2) {
  __shared__ __bf16 T[64][72];
  __shared__ float red[8];
  const int b = blockIdx.x;
  const int t = threadIdx.x;
  if (b < 8192) {  // ---- LayerNorm row b ----
    const float4 v = ((const float4*)(x + (size_t)b * 1024))[t];
    float s = v.x + v.y + v.z + v.w;
    float ss = v.x * v.x + v.y * v.y + v.z * v.z + v.w * v.w;
#pragma unroll
    for (int o = 32; o; o >>= 1) {
      s += __shfl_down(s, o);
      ss += __shfl_down(ss, o);
    }
    if ((t & 63) == 0) {
      red[t >> 6] = s;
      red[4 + (t >> 6)] = ss;
    }
    __syncthreads();
    const float tot = red[0] + red[1] + red[2] + red[3];
    const float tot2 = red[4] + red[5] + red[6] + red[7];
    const float mu = tot * (1.0f / 1024.0f);
    const float var = tot2 * (1.0f / 1024.0f) - mu * mu;
    const float rs = rsqrtf(var + 1e-5f);
    const float4 wv = ((const float4*)lw)[t];
    const float4 bv = ((const float4*)lb)[t];
    bf16x4 o;
    o[0] = (__bf16)((v.x - mu) * rs * wv.x + bv.x);
    o[1] = (__bf16)((v.y - mu) * rs * wv.y + bv.y);
    o[2] = (__bf16)((v.z - mu) * rs * wv.z + bv.z);
    o[3] = (__bf16)((v.w - mu) * rs * wv.w + bv.w);
    ((bf16x4*)xn)[(size_t)b * 256 + t] = o;
    return;
  }
  // ---- transpose+cvt 64x64 tile: A[R][C] -> At[C][R] ----
  const float* A;
  __bf16* At;
  int R, C, bx, by;
  if (b < 8960) {
    const int ti = b - 8192;           // 768 tiles: 48 x 16
    A = w_qkv; At = Wt1; R = 1024; C = 3072;
    bx = ti % 48; by = ti / 48;
  } else {
    const int ti = b - 8960;           // 256 tiles: 16 x 16
    A = w_out; At = Wt2; R = 1024; C = 1024;
    bx = ti % 16; by = ti / 16;
  }
  const int rb = by * 64, cb = bx * 64;
  const int r = t >> 2, cg = t & 3;
#pragma unroll
  for (int k = 0; k < 4; ++k) {
    const float4 v =
        *(const float4*)(A + (size_t)(rb + r) * C + cb + cg * 16 + k * 4);
    T[cg * 16 + k * 4 + 0][r] = (__bf16)v.x;
    T[cg * 16 + k * 4 + 1][r] = (__bf16)v.y;
    T[cg * 16 + k * 4 + 2][r] = (__bf16)v.z;
    T[cg * 16 + k * 4 + 3][r] = (__bf16)v.w;
  }
  __syncthreads();
#pragma unroll
  for (int i = 0; i < 2; ++i) {
    const int j = i * 256 + t;
    const int c = j >> 3, s8 = j & 7;
    const bf16x8 o = *(const bf16x8*)&T[c][s8 * 8];
    *(bf16x8*)(At + (size_t)(cb + c) * R + rb + s8 * 8) = o;
  }
}

// ---------------- NT-GEMM v2: C[M][N] = A[M][K] * B[N][K]^T ----------------
// (unchanged from R7) 128x256 tile, BK=64, 512 thr / 8 waves, 3-buffer LDS,
// lead-2 counted vmcnt(6), staging split around ks=0 MFMA, XCD-chunked remap.
template <int MODE>
__global__ __launch_bounds__(512) void gemm_nt(
    const __bf16* __restrict__ A, const __bf16* __restrict__ B, int K,
    float* __restrict__ outF, __bf16* __restrict__ Qo, __bf16* __restrict__ Ko,
    __bf16* __restrict__ Vto, const float* __restrict__ bias) {
  __shared__ __bf16 Sm[3 * 24576];  // per buf: A[128][64] @0, B[256][64] @8192
  const int tid = threadIdx.x;
  const int lane = tid & 63, w = tid >> 6;
  const int g = lane >> 4, c15 = lane & 15;
  const int wr = w >> 2, wc = w & 3;  // wave tile: rows wr*64, cols wc*64
  const int linear = blockIdx.y * gridDim.x + blockIdx.x;
  const int per = (gridDim.x * gridDim.y) >> 3;
  const int nl = (linear & 7) * per + (linear >> 3);
  const int rb = (nl / gridDim.x) * 128, cb = (nl % gridDim.x) * 256;

  const __bf16* aSp[2];
  const __bf16* bSp[4];
  int aDo[2], bDo[4];
#pragma unroll
  for (int i = 0; i < 2; ++i) {
    const int j = i * 512 + tid, row = j >> 3, slot = j & 7;
    aSp[i] = A + (size_t)(rb + row) * K + ((slot ^ (row & 7)) << 3);
    aDo[i] = i * 4096 + w * 512;
  }
#pragma unroll
  for (int i = 0; i < 4; ++i) {
    const int j = i * 512 + tid, col = j >> 3, slot = j & 7;
    bSp[i] = B + (size_t)(cb + col) * K + ((slot ^ (col & 7)) << 3);
    bDo[i] = 8192 + i * 4096 + w * 512;
  }

  f32x4 acc[4][4] = {};
  const int nkb = K >> 6;  // 16

#pragma unroll
  for (int t = 0; t < 2; ++t) {
    __bf16* dst = Sm + t * 24576;
#pragma unroll
    for (int i = 0; i < 2; ++i) GLOAD16(aSp[i] + t * 64, dst + aDo[i]);
#pragma unroll
    for (int i = 0; i < 4; ++i) GLOAD16(bSp[i] + t * 64, dst + bDo[i]);
  }

  int cur = 0, stg = 2, koff = 128;
  for (int kb = 0; kb < nkb; ++kb) {
    if (kb == nkb - 1) {
      asm volatile("s_waitcnt vmcnt(0)" ::: "memory");
    } else {
      asm volatile("s_waitcnt vmcnt(6)" ::: "memory");
    }
    __builtin_amdgcn_s_barrier();
    const bool do_stage = (kb < nkb - 2);
    __bf16* sdst = Sm + stg * 24576;
    if (do_stage) {
#pragma unroll
      for (int i = 0; i < 2; ++i) GLOAD16(aSp[i] + koff, sdst + aDo[i]);
    }
    const __bf16* __restrict__ Ac = Sm + cur * 24576;
    const __bf16* __restrict__ Bc = Ac + 8192;
    // ks = 0
    {
      bf16x8 af[4], bfr[4];
      const int kc = g;
#pragma unroll
      for (int rt = 0; rt < 4; ++rt) {
        const int lr = wr * 64 + rt * 16 + c15;
        af[rt] = *(const bf16x8*)(Ac + lr * 64 + ((kc ^ (lr & 7)) << 3));
      }
#pragma unroll
      for (int ct = 0; ct < 4; ++ct) {
        const int lc = wc * 64 + ct * 16 + c15;
        bfr[ct] = *(const bf16x8*)(Bc + lc * 64 + ((kc ^ (lc & 7)) << 3));
      }
      __builtin_amdgcn_s_setprio(1);
#pragma unroll
      for (int rt = 0; rt < 4; ++rt)
#pragma unroll
        for (int ct = 0; ct < 4; ++ct)
          acc[rt][ct] = __builtin_amdgcn_mfma_f32_16x16x32_bf16(
              af[rt], bfr[ct], acc[rt][ct], 0, 0, 0);
      __builtin_amdgcn_s_setprio(0);
    }
    if (do_stage) {
#pragma unroll
      for (int i = 0; i < 4; ++i) GLOAD16(bSp[i] + koff, sdst + bDo[i]);
      koff += 64;
    }
    // ks = 1
    {
      bf16x8 af[4], bfr[4];
      const int kc = 4 + g;
#pragma unroll
      for (int rt = 0; rt < 4; ++rt) {
        const int lr = wr * 64 + rt * 16 + c15;
        af[rt] = *(const bf16x8*)(Ac + lr * 64 + ((kc ^ (lr & 7)) << 3));
      }
#pragma unroll
      for (int ct = 0; ct < 4; ++ct) {
        const int lc = wc * 64 + ct * 16 + c15;
        bfr[ct] = *(const bf16x8*)(Bc + lc * 64 + ((kc ^ (lc & 7)) << 3));
      }
      __builtin_amdgcn_s_setprio(1);
#pragma unroll
      for (int rt = 0; rt < 4; ++rt)
#pragma unroll
        for (int ct = 0; ct < 4; ++ct)
          acc[rt][ct] = __builtin_amdgcn_mfma_f32_16x16x32_bf16(
              af[rt], bfr[ct], acc[rt][ct], 0, 0, 0);
      __builtin_amdgcn_s_setprio(0);
    }
    cur = (cur == 2) ? 0 : cur + 1;
    stg = (stg == 2) ? 0 : stg + 1;
  }
  const int r00 = rb + wr * 64 + g * 4;
  if (MODE == 1) {
#pragma unroll
    for (int ct = 0; ct < 4; ++ct) {
      const int col = cb + wc * 64 + ct * 16 + c15;
      const float bv = bias[col];
#pragma unroll
      for (int rt = 0; rt < 4; ++rt) {
        const int row = r00 + rt * 16;
#pragma unroll
        for (int r = 0; r < 4; ++r)
          outF[(size_t)(row + r) * 1024 + col] = acc[rt][ct][r] + bv;
      }
    }
  } else {
#pragma unroll
    for (int ct = 0; ct < 4; ++ct) {
      const int col = cb + wc * 64 + ct * 16 + c15;  // 0..3071
      const int part = col >> 10, rem = col & 1023;
      const int h = rem >> 6, d = rem & 63;
#pragma unroll
      for (int rt = 0; rt < 4; ++rt) {
        const int row = r00 + rt * 16;  // 0..8191
        const int bi = row >> 11, n = row & 2047;
        const size_t bh = (size_t)bi * 16 + h;
        if (part == 2) {  // V stored transposed: Vt[bh][d][n]
          bf16x4 pv;
#pragma unroll
          for (int r = 0; r < 4; ++r) pv[r] = (__bf16)acc[rt][ct][r];
          *(bf16x4*)(Vto + (bh * 64 + d) * 2048 + n) = pv;
        } else if (part == 0) {  // Q: [bh][n][d], pre-scaled by PSCALE
          __bf16* dst = Qo + (bh * 2048 + n) * 64 + d;
#pragma unroll
          for (int r = 0; r < 4; ++r)
            dst[(size_t)r * 64] = (__bf16)(acc[rt][ct][r] * PSCALE);
        } else {  // K: [bh][n][d]
          __bf16* dst = Ko + (bh * 2048 + n) * 64 + d;
#pragma unroll
          for (int r = 0; r < 4; ++r) dst[(size_t)r * 64] = (__bf16)acc[rt][ct][r];
        }
      }
    }
  }
}

// ------------- fused relu-attention: O = relu(Q' K^T) @ V  (Q' pre-scaled) --
// v6: 32x32x16 MFMA (969 vs 844 FLOP/cyc/SIMD, half the issue slots).
// Swapped QK^T: S^T = mfma32(K_frag, Q_frag) -> col=q=lane&31,
// row(key)=(r&3)+8(r>>2)+4hi. K staged with row permutation kappa = swap
// bits 2<->3, so D regs 8w..8w+7 hold keys 16w+8hi+{0..7} -- contiguous in
// element index; with A/B layout symmetry these feed PV's A operand directly,
// and V is read as 8 contiguous keys from base 16w+8hi (b128, d&15 XOR ->
// address-broadcast pairs = conflict-free). 16 QK + 16 PV MFMAs/wave/kb.
__global__ __launch_bounds__(512, 4) void attn_relu(
    const __bf16* __restrict__ Q, const __bf16* __restrict__ K,
    const __bf16* __restrict__ Vt, __bf16* __restrict__ O) {
  __shared__ __bf16 Ks[2][128 * 64];   // 2 x 16 KB
  __shared__ __bf16 Vs[2][64 * 128];   // 2 x 16 KB
  const int tid = threadIdx.x;
  const int lane = tid & 63, wv = tid >> 6;  // wv: 0..7
  const int hi = lane >> 5, c31 = lane & 31;
  const int bh = blockIdx.x, qb = blockIdx.y;
  const __bf16* Qg = Q + ((size_t)bh * 2048 + qb * 256) * 64;
  const __bf16* Kg = K + (size_t)bh * 2048 * 64;
  const __bf16* Vg = Vt + (size_t)bh * 64 * 2048;

  // hoisted staging sources (1024 16B chunks/tile, 512 thr):
  // K: LDS row X holds global key kappa(X) = bits2<->3 swapped; d-chunk slot
  //    s holds global d-chunk s ^ (X&7).
  // V: LDS chunk (d, slot) holds global key-chunk (slot ^ (d&15)).
  const __bf16* kp0;
  const __bf16* kp1;
  const __bf16* vp0;
  const __bf16* vp1;
  {
    const int j0 = tid, j1 = 512 + tid;
    const int X0 = j0 >> 3, s0 = j0 & 7;
    const int X1 = j1 >> 3, s1 = j1 & 7;
    const int K0 = (X0 & ~12) | ((X0 & 4) << 1) | ((X0 & 8) >> 1);
    const int K1 = (X1 & ~12) | ((X1 & 4) << 1) | ((X1 & 8) >> 1);
    kp0 = Kg + (size_t)K0 * 64 + ((s0 ^ (X0 & 7)) << 3);
    kp1 = Kg + (size_t)K1 * 64 + ((s1 ^ (X1 & 7)) << 3);
    const int d0_ = j0 >> 4, t0_ = j0 & 15;
    const int d1_ = j1 >> 4, t1_ = j1 & 15;
    vp0 = Vg + (size_t)d0_ * 2048 + ((t0_ ^ (d0_ & 15)) << 3);
    vp1 = Vg + (size_t)d1_ * 2048 + ((t1_ ^ (d1_ & 15)) << 3);
  }
  const int dstoff = wv * 64 * 8;  // wave-uniform LDS chunk base (elements)

  // Q B-frags: lane holds q = wv*32 + c31, d = dw*16 + hi*8 + {0..7}
  bf16x8 qf[4];
#pragma unroll
  for (int dw = 0; dw < 4; ++dw)
    qf[dw] = *(const bf16x8*)(Qg + (wv * 32 + c31) * 64 + dw * 16 + hi * 8);
  f32x16 oacc[2] = {};  // O[q][d=dc*32+c31], q from reg per C/D map

  // prologue: stage tile 0 into buffer 0 (4 gload_lds per thread per tile)
  GLOAD16(kp0, Ks[0] + dstoff);
  GLOAD16(kp1, Ks[0] + 512 * 8 + dstoff);
  GLOAD16(vp0, Vs[0] + dstoff);
  GLOAD16(vp1, Vs[0] + 512 * 8 + dstoff);
  kp0 += 128 * 64; kp1 += 128 * 64; vp0 += 128; vp1 += 128;

  for (int kb = 0; kb < 16; ++kb) {
    const int cur = kb & 1;
    if (kb < 15) {
      GLOAD16(kp0, Ks[cur ^ 1] + dstoff);
      GLOAD16(kp1, Ks[cur ^ 1] + 512 * 8 + dstoff);
      GLOAD16(vp0, Vs[cur ^ 1] + dstoff);
      GLOAD16(vp1, Vs[cur ^ 1] + 512 * 8 + dstoff);
      kp0 += 128 * 64; kp1 += 128 * 64; vp0 += 128; vp1 += 128;
      asm volatile("s_waitcnt vmcnt(4)" ::: "memory");
    } else {
      asm volatile("s_waitcnt vmcnt(0)" ::: "memory");
    }
    __builtin_amdgcn_s_barrier();  // cur tile staged for all waves
    const __bf16* __restrict__ Kc = Ks[cur];
    const __bf16* __restrict__ Vc = Vs[cur];
#pragma unroll
    for (int kb32 = 0; kb32 < 4; ++kb32) {  // 32-key blocks
      // K A-frags: row = kb32*32 + c31, d-chunk (2dw+hi) ^ (row&7)
      bf16x8 kf[4];
      const int R = kb32 * 32 + c31;
#pragma unroll
      for (int dw = 0; dw < 4; ++dw)
        kf[dw] =
            *(const bf16x8*)(Kc + R * 64 + (((2 * dw + hi) ^ (R & 7)) << 3));
      f32x16 s = {};
      __builtin_amdgcn_s_setprio(1);
#pragma unroll
      for (int dw = 0; dw < 4; ++dw)
        s = __builtin_amdgcn_mfma_f32_32x32x16_bf16(kf[dw], qf[dw], s, 0, 0, 0);
      __builtin_amdgcn_s_setprio(0);
      // relu -> bf16: window wl regs 8wl..8wl+7 = keys 16*(2kb32+wl)+8hi+e
      bf16x8 pa[2];
#pragma unroll
      for (int wl = 0; wl < 2; ++wl)
#pragma unroll
        for (int e = 0; e < 8; ++e)
          pa[wl][e] = (__bf16)fmaxf(s[8 * wl + e], 0.0f);
      __builtin_amdgcn_s_setprio(1);
#pragma unroll
      for (int wl = 0; wl < 2; ++wl) {
        const int win = 2 * kb32 + wl;
#pragma unroll
        for (int dc = 0; dc < 2; ++dc) {
          const int d = dc * 32 + c31;
          const bf16x8 vb = *(const bf16x8*)(
              Vc + d * 128 + (((2 * win + hi) ^ (d & 15)) << 3));
          oacc[dc] = __builtin_amdgcn_mfma_f32_32x32x16_bf16(pa[wl], vb,
                                                             oacc[dc], 0, 0, 0);
        }
      }
      __builtin_amdgcn_s_setprio(0);
    }
    __builtin_amdgcn_s_barrier();  // all waves done reading cur before restage
  }
  // write O merged-head: [b][n][h*64+d] bf16; q = wv*32+(r&3)+8(r>>2)+4hi
  const int bi = bh >> 4, h = bh & 15;
#pragma unroll
  for (int dc = 0; dc < 2; ++dc) {
    const int col = h * 64 + dc * 32 + c31;
#pragma unroll
    for (int r = 0; r < 16; ++r) {
      const int q = wv * 32 + (r & 3) + 8 * (r >> 2) + 4 * hi;
      const int n0 = qb * 256 + q;
      O[((size_t)bi * 2048 + n0) * 1024 + col] = (__bf16)oacc[dc][r];
    }
  }
}

extern "C" void kernel_launch(void* const* d_in, const int* in_sizes, int n_in,
                              void* d_out, int out_size, void* d_ws,
                              size_t ws_size, hipStream_t stream) {
  (void)in_sizes; (void)n_in; (void)out_size; (void)ws_size;
  const float* x = (const float*)d_in[0];
  const float* ln_w = (const float*)d_in[1];
  const float* ln_b = (const float*)d_in[2];
  const float* w_qkv = (const float*)d_in[3];
  const float* w_out = (const float*)d_in[4];
  const float* b_out = (const float*)d_in[5];
  // d_in[6] = layer_index == 2 (< DEPTH/2) -> relu branch only.
  char* ws = (char*)d_ws;
  __bf16* xn = (__bf16*)(ws);                           // 16 MB
  __bf16* Wt1 = (__bf16*)(ws + (size_t)(16u << 20));    // 6 MB  [3072][1024]
  __bf16* Wt2 = (__bf16*)(ws + (size_t)(22u << 20));    // 2 MB  [1024][1024]
  __bf16* Qb = (__bf16*)(ws + (size_t)(24u << 20));     // 16 MB [64][2048][64]
  __bf16* Kb = (__bf16*)(ws + (size_t)(40u << 20));     // 16 MB
  __bf16* Vtb = (__bf16*)(ws + (size_t)(56u << 20));    // 16 MB [64][64][2048]
  __bf16* Ob = (__bf16*)(ws + (size_t)(72u << 20));     // 16 MB [8192][1024]
  float* out = (float*)d_out;

  prep<<<9216, 256, 0, stream>>>(x, ln_w, ln_b, xn, w_qkv, Wt1, w_out, Wt2);
  gemm_nt<0><<<dim3(12, 64), 512, 0, stream>>>(xn, Wt1, 1024, nullptr, Qb, Kb,
                                               Vtb, nullptr);
  attn_relu<<<dim3(64, 8), 512, 0, stream>>>(Qb, Kb, Vtb, Ob);
  gemm_nt<1><<<dim3(4, 64), 512, 0, stream>>>(Ob, Wt2, 1024, out, nullptr,
                                              nullptr, nullptr, b_out);
}